// Round 8
// baseline (383.956 us; speedup 1.0000x reference)
//
#include <hip/hip_runtime.h>

#define DIM 4096
// SCALE = 1/sqrt(4096) = 1/64: exact pow2; folding into gauss is bitwise-safe.
#define FF_SCALE 0.015625f

typedef __attribute__((ext_vector_type(2))) float f32x2;

// Packed dual-FP32 (VOP3P). Per-half rounding identical to scalar v_add_f32
// -> bitwise-identical butterflies (r6 measured absmax=0.0).
static __device__ __forceinline__ f32x2 pk_add(f32x2 a, f32x2 b) {
    f32x2 d; asm("v_pk_add_f32 %0, %1, %2" : "=v"(d) : "v"(a), "v"(b)); return d;
}
static __device__ __forceinline__ f32x2 pk_sub(f32x2 a, f32x2 b) {
    f32x2 d;
    asm("v_pk_add_f32 %0, %1, %2 neg_lo:[0,1] neg_hi:[0,1]" : "=v"(d) : "v"(a), "v"(b));
    return d;
}
static __device__ __forceinline__ f32x2 pk_mul(f32x2 a, f32x2 b) {
    f32x2 d; asm("v_pk_mul_f32 %0, %1, %2" : "=v"(d) : "v"(a), "v"(b)); return d;
}
static __device__ __forceinline__ f32x2 pk_fma(f32x2 a, f32x2 b, f32x2 c) {
    f32x2 d; asm("v_pk_fma_f32 %0, %1, %2, %3" : "=v"(d) : "v"(a), "v"(b), "v"(c));
    return d;
}

// 16-point FWHT on 8 packed pairs, ascending stage order (r6-proven bitwise).
static __device__ __forceinline__ void fwht16_pk(f32x2 p[8]) {
#pragma unroll
    for (int m = 0; m < 8; ++m) {
        float a = p[m].x, b = p[m].y;
        p[m].x = a + b;
        p[m].y = a - b;
    }
#pragma unroll
    for (int h2 = 1; h2 < 8; h2 <<= 1) {
#pragma unroll
        for (int m = 0; m < 8; ++m)
            if ((m & h2) == 0) {
                f32x2 a = p[m], b = p[m + h2];
                p[m] = pk_add(a, b);
                p[m + h2] = pk_sub(a, b);
            }
    }
}

// quad_perm DPP exchange on a packed pair (2x mov_dpp, pure VALU).
// 0xB1 = lane^1, 0x4E = lane^2.
template <int CTRL>
static __device__ __forceinline__ f32x2 qperm2(f32x2 x) {
    f32x2 r;
    r.x = __int_as_float(__builtin_amdgcn_mov_dpp(__float_as_int(x.x), CTRL, 0xF, 0xF, true));
    r.y = __int_as_float(__builtin_amdgcn_mov_dpp(__float_as_int(x.y), CTRL, 0xF, 0xF, true));
    return r;
}
// Packed butterfly over a quad lane-bit: low lane v+p, high lane p-v
// (pk_fma with s=+-1 splat: exact, identical rounding to a+b / a-b).
template <int CTRL>
static __device__ __forceinline__ void qb_pk(f32x2 p[8], f32x2 s) {
#pragma unroll
    for (int e = 0; e < 8; ++e) p[e] = pk_fma(p[e], s, qperm2<CTRL>(p[e]));
}

// LDS layout: float index i at dword addr i + 4*(i>>8).
//  - R1 b128 writes at 16t+4(t>>4): quad-slot (4t+(t>>4))%8 -> 8 lanes/slot,
//    structurally optimal.
//  - R2 stride-64 scalar ops: bank = ((t>>2) + 16*(t&3))%32 -> exactly 2-way
//    (free, m136). Addressing affine: base + (64m + 4*(m>>2)) immediates.
static __device__ __forceinline__ int pad(int i) { return i + ((i >> 8) << 2); }

// radix-64 x radix-64 FWHT per row (r2's proven decomposition, r6's pk ops):
//  R1: thread t owns contiguous i=16t+e: h=1..8 regs, h=16,32 DPP (lane^1,^2)
//  R2: thread t owns i=1024(t&3)+64m+(t>>2), m=0..15:
//      h=64..512 regs, h=1024,2048 DPP (lane^1,^2)
// Ascending global stage order -> bitwise-identical tree to the reference.
__global__ __launch_bounds__(256, 8) void fastfood_kernel(
    const float* __restrict__ x,
    const float* __restrict__ d1,
    const float* __restrict__ d2,
    const float* __restrict__ gauss_d,
    const int* __restrict__ perm,
    float* __restrict__ out)
{
    __shared__ float lds[DIM + 60];  // 16.6 KB -> 8 blocks/CU
    const int t = threadIdx.x;
    const size_t rowoff = (size_t)blockIdx.x * DIM;
    const float sg1 = (t & 1) ? -1.f : 1.f;
    const float sg2 = (t & 2) ? -1.f : 1.f;
    const f32x2 s1 = {sg1, sg1};
    const f32x2 s2 = {sg2, sg2};
    const int wbase = 16 * t + ((t >> 4) << 2);          // pad(16t)
    const int rbase = 1040 * (t & 3) + (t >> 2);         // pad(1024(t&3)+(t>>2))
    const int ibase = ((t & 3) << 10) + (t >> 2);        // logical i base, R2

    f32x2 p[8];

    // ---- load x*d1 (contiguous float4, coalesced) ----
    {
        const float4* xv = (const float4*)(x + rowoff + t * 16);
        const float4* dv = (const float4*)(d1 + t * 16);
#pragma unroll
        for (int q = 0; q < 4; ++q) {
            float4 aa = xv[q], dd = dv[q];
            p[2 * q]     = pk_mul((f32x2){aa.x, aa.y}, (f32x2){dd.x, dd.y});
            p[2 * q + 1] = pk_mul((f32x2){aa.z, aa.w}, (f32x2){dd.z, dd.w});
        }
    }

    // ---- FWHT1 R1: h=1..8 (regs) + 16,32 (DPP) ----
    fwht16_pk(p);
    qb_pk<0xB1>(p, s1);
    qb_pk<0x4E>(p, s2);
#pragma unroll
    for (int q = 0; q < 4; ++q)
        *(float4*)(lds + wbase + 4 * q) =
            make_float4(p[2 * q].x, p[2 * q].y, p[2 * q + 1].x, p[2 * q + 1].y);
    __syncthreads();  // B1

    // ---- FWHT1 R2: h=64..512 (regs) + 1024,2048 (DPP) ----
#pragma unroll
    for (int m = 0; m < 8; ++m) {
        f32x2 w;
        w.x = lds[rbase + (128 * m + 4 * ((2 * m) >> 2))];
        w.y = lds[rbase + (128 * m + 64 + 4 * ((2 * m + 1) >> 2))];
        p[m] = w;
    }
    fwht16_pk(p);
    qb_pk<0xB1>(p, s1);
    qb_pk<0x4E>(p, s2);
#pragma unroll
    for (int m = 0; m < 8; ++m) {
        lds[rbase + (128 * m + 4 * ((2 * m) >> 2))]      = p[m].x;
        lds[rbase + (128 * m + 64 + 4 * ((2 * m + 1) >> 2))] = p[m].y;
    }
    __syncthreads();  // B2: FWHT1 fully in LDS

    // ---- permutation gather + gauss*SCALE (contiguous j = 16t+k) ----
    {
        const int4* pv = (const int4*)(perm + t * 16);
        const float4* gv = (const float4*)(gauss_d + t * 16);
#pragma unroll
        for (int q = 0; q < 4; ++q) {
            int4 p4 = pv[q];
            float4 g4 = gv[q];
            f32x2 lo, hi;
            lo.x = lds[pad(p4.x)];
            lo.y = lds[pad(p4.y)];
            hi.x = lds[pad(p4.z)];
            hi.y = lds[pad(p4.w)];
            f32x2 gs0 = pk_mul((f32x2){g4.x, g4.y}, (f32x2){FF_SCALE, FF_SCALE});
            f32x2 gs1 = pk_mul((f32x2){g4.z, g4.w}, (f32x2){FF_SCALE, FF_SCALE});
            p[2 * q]     = pk_mul(lo, gs0);
            p[2 * q + 1] = pk_mul(hi, gs1);
        }
    }

    // ---- FWHT2 R1 (register/DPP only) ----
    fwht16_pk(p);
    qb_pk<0xB1>(p, s1);
    qb_pk<0x4E>(p, s2);
    __syncthreads();  // B3: all gather reads done before overwrite
#pragma unroll
    for (int q = 0; q < 4; ++q)
        *(float4*)(lds + wbase + 4 * q) =
            make_float4(p[2 * q].x, p[2 * q].y, p[2 * q + 1].x, p[2 * q + 1].y);
    __syncthreads();  // B4

    // ---- FWHT2 R2 + fused d2 epilogue ----
#pragma unroll
    for (int m = 0; m < 8; ++m) {
        f32x2 w;
        w.x = lds[rbase + (128 * m + 4 * ((2 * m) >> 2))];
        w.y = lds[rbase + (128 * m + 64 + 4 * ((2 * m + 1) >> 2))];
        p[m] = w;
    }
    fwht16_pk(p);
    qb_pk<0xB1>(p, s1);
    qb_pk<0x4E>(p, s2);
    {
        const float* d2p = d2 + ibase;
        float* op = out + rowoff + ibase;
#pragma unroll
        for (int m = 0; m < 8; ++m) {
            f32x2 dd;
            dd.x = d2p[128 * m];
            dd.y = d2p[128 * m + 64];
            f32x2 r = pk_mul(p[m], dd);
            // per instr: 4 segments x 64 contiguous bytes
            op[128 * m]      = r.x;
            op[128 * m + 64] = r.y;
        }
    }
}

// ---- BW probe at the exact production launch shape (8192 x 256, 16KB rows).
// Launched BEFORE fastfood_kernel: writes garbage to d_out, which the real
// kernel then overwrites -> validation unaffected. Deliberately the slowest
// dispatch so it owns the top-5 rocprof rows: dur + FETCH/WRITE give the
// achievable copy BW at this shape (3 read+write passes over rotated rows).
__global__ __launch_bounds__(256) void probe_copy3(
    const float* __restrict__ x, float* __restrict__ o)
{
    const int t = threadIdx.x;
#pragma unroll
    for (int r = 0; r < 3; ++r) {
        const int row = (int)((blockIdx.x + r * 2731u) & 8191u);
        const size_t off = (size_t)row * DIM + t * 16;
        const float4* xv = (const float4*)(x + off);
        float4* ov = (float4*)(o + off);
        const float s = (float)(r + 1);
#pragma unroll
        for (int q = 0; q < 4; ++q) {
            float4 a = xv[q];
            a.x *= s; a.y *= s; a.z *= s; a.w *= s;
            ov[q] = a;
        }
    }
}

extern "C" void kernel_launch(void* const* d_in, const int* in_sizes, int n_in,
                              void* d_out, int out_size, void* d_ws, size_t ws_size,
                              hipStream_t stream) {
    const float* x       = (const float*)d_in[0];
    const float* d1      = (const float*)d_in[1];
    const float* d2      = (const float*)d_in[2];
    const float* gauss_d = (const float*)d_in[3];
    const int*   perm    = (const int*)d_in[4];
    float* out = (float*)d_out;

    const int batch = in_sizes[0] / DIM;  // 8192

    // 1) BW probe (garbage into d_out; overwritten below)
    probe_copy3<<<batch, 256, 0, stream>>>(x, out);
    // 2) real kernel (correct output)
    fastfood_kernel<<<batch, 256, 0, stream>>>(x, d1, d2, gauss_d, perm, out);
}